// Round 2
// 213.533 us; speedup vs baseline: 1.0238x; 1.0238x over previous
//
#include <hip/hip_runtime.h>
#include <hip/hip_bf16.h>
#include <stdint.h>

// Problem constants (B=16, C=256, NH=4, D=64, G=32, L=HW=1024)
// Round 18 (resubmit; R1 bench was an infra failure, no counters returned).
// Drop K/V LDS staging in attn entirely. R17 counters: attn 87.8us,
// MfmaUtil 7.6%, VALUBusy 41%, 6.8M LDS bank-conflict cycles, HBM 12% ->
// staging/sync/VALU-bound, not roofline. K/V per (b,head) = 256KB, L2-fits
// and is reused by 32 q-blocks => staging is pure overhead (learn_hip
// common-mistake #7). MFMA A/B frags are contiguous 16B slices of global
// K^T [l][64] / V [d][1024], so read them directly: zero barriers in the
// main loop, waves independent, compiler free to pipeline chunks.
// P->A-frag transpose moved from 32 ds_bpermute/chunk to a per-wave 2KB LDS
// bounce (4x ds_write_b64 + lgkmcnt(0) + 2x ds_read_b128, conflict-free,
// wave-private region aliased under the combine buffer; asm memory fences
// pin the cross-lane exchange ordering). Score scale 1/8 folded into Q at
// the qkv-GEMM epilogue (exact pow2). All other kernels unchanged.

typedef __hip_bfloat16 bf16;
typedef __attribute__((ext_vector_type(8))) short short8;
typedef __attribute__((ext_vector_type(4))) short short4v;
typedef __attribute__((ext_vector_type(4))) float float4v;

__global__ __launch_bounds__(256) void stats_kernel(const float* __restrict__ x,
    float2* __restrict__ stats) {
  int b = blockIdx.x >> 5, g = blockIdx.x & 31;
  const float* xp = x + (size_t)(b * 256 + g * 8) * 1024;
  float s = 0.f, ss = 0.f;
  for (int i = threadIdx.x; i < 8192; i += 256) {
    float v = xp[i]; s += v; ss += v * v;
  }
  #pragma unroll
  for (int o = 32; o; o >>= 1) { s += __shfl_down(s, o); ss += __shfl_down(ss, o); }
  __shared__ float red[2][4];
  int wid = threadIdx.x >> 6;
  if ((threadIdx.x & 63) == 0) { red[0][wid] = s; red[1][wid] = ss; }
  __syncthreads();
  if (threadIdx.x == 0) {
    s  = red[0][0] + red[0][1] + red[0][2] + red[0][3];
    ss = red[1][0] + red[1][1] + red[1][2] + red[1][3];
    float mean = s * (1.f / 8192.f);
    float var  = ss * (1.f / 8192.f) - mean * mean;
    stats[blockIdx.x] = make_float2(mean, rsqrtf(var + 1e-5f));
  }
}

// GN + transpose: hT[zb][l][c] = GN(x)[b][c][l], bf16.
__global__ __launch_bounds__(256) void gnt_kernel(const float* __restrict__ x,
    const float* __restrict__ gamma, const float* __restrict__ beta,
    const float2* __restrict__ stats, bf16* __restrict__ hT, int b_off) {
  __shared__ float T[64][65];
  int zb = blockIdx.z, b = zb + b_off;
  int c0 = blockIdx.y * 64, l0 = blockIdx.x * 64;
  const float* xb = x + (size_t)b * 262144;
  const float2* st = stats + b * 32;
  int tid = threadIdx.x;
  for (int i = tid; i < 4096; i += 256) {
    int cl = i >> 6, ll = i & 63;
    int c = c0 + cl;
    float2 s2 = st[c >> 3];
    T[cl][ll] = (xb[(size_t)c * 1024 + l0 + ll] - s2.x) * s2.y * gamma[c] + beta[c];
  }
  __syncthreads();
  bf16* hb = hT + (size_t)zb * 262144;
  for (int i = tid; i < 4096; i += 256) {
    int ll = i >> 6, cl = i & 63;
    hb[(size_t)(l0 + ll) * 256 + c0 + cl] = __float2bfloat16(T[cl][ll]);
  }
}

__global__ __launch_bounds__(256) void wpack(const float* __restrict__ wq,
    const float* __restrict__ wk, const float* __restrict__ wv,
    const float* __restrict__ wp, bf16* __restrict__ Wb, bf16* __restrict__ Pb) {
  int i = blockIdx.x * 256 + threadIdx.x;        // 262144 total
  if (i < 196608) {
    int r = i >> 8, c = i & 255;
    const float* src = (r < 256) ? wq : (r < 512) ? wk : wv;
    Wb[i] = __float2bfloat16(src[(r & 255) * 256 + c]);
  } else {
    int j = i - 196608;
    Pb[j] = __float2bfloat16(wp[j]);
  }
}

// qkv GEMM on MFMA: C[m][l] = Wb[m][:]·h[:][l] + bias. B^T = hT rows.
// Q section (sec==0) pre-scaled by 1/8 (attention score scale, exact pow2).
__global__ __launch_bounds__(256) void gemm_qkv_mfma(
    const bf16* __restrict__ hT, const bf16* __restrict__ Wb,
    const float* __restrict__ bq, const float* __restrict__ bk,
    const float* __restrict__ bv,
    bf16* __restrict__ qkv, size_t qkv_bstride) {
  __shared__ bf16 As[128][40];
  __shared__ bf16 Bs[128][40];
  int zb = blockIdx.z;
  int m0 = blockIdx.y * 128, l0 = blockIdx.x * 128;
  const bf16* hb = hT + (size_t)zb * 262144;
  int tid = threadIdx.x, lane = tid & 63, wave = tid >> 6;
  int l16 = lane & 15, quad = lane >> 4;
  int mi0 = (wave & 1) * 4, nj0 = (wave >> 1) * 4;
  float4v acc[4][4];
  #pragma unroll
  for (int i = 0; i < 4; i++)
    #pragma unroll
    for (int j = 0; j < 4; j++) acc[i][j] = (float4v){0.f, 0.f, 0.f, 0.f};

  for (int kc = 0; kc < 8; kc++) {
    __syncthreads();
    #pragma unroll
    for (int it = 0; it < 2; it++) {
      int s = it * 256 + tid;
      int mm = s >> 2, kk = (s & 3) * 8;
      *(short8*)&As[mm][kk] = *(const short8*)&Wb[(size_t)(m0 + mm) * 256 + kc * 32 + kk];
      *(short8*)&Bs[mm][kk] = *(const short8*)&hb[(size_t)(l0 + mm) * 256 + kc * 32 + kk];
    }
    __syncthreads();
    short8 af[4], bfr[4];
    #pragma unroll
    for (int i = 0; i < 4; i++) af[i]  = *(const short8*)&As[(mi0 + i) * 16 + l16][quad * 8];
    #pragma unroll
    for (int j = 0; j < 4; j++) bfr[j] = *(const short8*)&Bs[(nj0 + j) * 16 + l16][quad * 8];
    #pragma unroll
    for (int i = 0; i < 4; i++)
      #pragma unroll
      for (int j = 0; j < 4; j++)
        acc[i][j] = __builtin_amdgcn_mfma_f32_16x16x32_bf16(af[i], bfr[j], acc[i][j], 0, 0, 0);
  }

  bf16* Cp = qkv + (size_t)zb * qkv_bstride;
  int sec = m0 >> 8;
  const float* bptr = (sec == 0) ? bq : (sec == 1) ? bk : bv;
  #pragma unroll
  for (int i = 0; i < 4; i++) {
    #pragma unroll
    for (int r = 0; r < 4; r++) {
      int m = m0 + (mi0 + i) * 16 + quad * 4 + r;
      float bias = bptr[m & 255];
      if (sec == 1) {
        int rr = m & 255;
        bf16* Kp = Cp + 256 * 1024 + (rr >> 6) * 65536;
        #pragma unroll
        for (int j = 0; j < 4; j++) {
          int l = l0 + (nj0 + j) * 16 + l16;
          Kp[(size_t)l * 64 + (rr & 63)] = __float2bfloat16(acc[i][j][r] + bias);
        }
      } else {
        float sc = (sec == 0) ? 0.125f : 1.0f;
        #pragma unroll
        for (int j = 0; j < 4; j++) {
          int l = l0 + (nj0 + j) * 16 + l16;
          Cp[(size_t)m * 1024 + l] = __float2bfloat16((acc[i][j][r] + bias) * sc);
        }
      }
    }
  }
}

// Flash MFMA attention, stagingless: one block per (b, head, 32 q-rows);
// per-wave online softmax over its 32-key slice of each 128-key chunk.
// K^T/V fragment loads go straight to global (L2-resident); no barriers in
// the main loop. P transpose via wave-private 2KB LDS bounce.
__global__ __launch_bounds__(256) void attn_kernel(
    const bf16* __restrict__ qkv, bf16* __restrict__ oT,
    size_t qkv_bstride, size_t o_bstride) {
  __shared__ __align__(16) char lds_raw[34304];
  bf16*  Pl = (bf16*)lds_raw;                    // loop phase: [4 waves][32 q][32 key] = 8 KB
  float* Ow = (float*)lds_raw;                   // combine alias: 4x32x65 f32 = 33280 B
  float* mS = (float*)(lds_raw + 33280);         // [4][32]
  float* lS = (float*)(lds_raw + 33792);         // [4][32]

  int zb = blockIdx.z, n = blockIdx.y;
  int q0 = blockIdx.x * 32;
  const bf16* base = qkv + (size_t)zb * qkv_bstride;
  const bf16* Qp  = base + (size_t)(n * 64) * 1024;
  const bf16* KTp = base + (size_t)256 * 1024 + (size_t)n * 65536;  // [l][64]
  const bf16* Vp  = base + (size_t)512 * 1024 + (size_t)(n * 64) * 1024;
  int tid = threadIdx.x;
  int lane = tid & 63, wave = tid >> 6;
  int l16 = lane & 15, quad = lane >> 4;
  bf16* Pw = Pl + wave * 1024;                   // wave-private P[q(32)][key(32)]

  // B-frags (Q), 2 q-subtiles: qf[t][h][j] = Q[h*32+quad*8+j][q0+t*16+l16]
  short8 qf[2][2];
  #pragma unroll
  for (int t = 0; t < 2; t++)
    #pragma unroll
    for (int h = 0; h < 2; h++)
      #pragma unroll
      for (int j = 0; j < 8; j++)
        ((short*)&qf[t][h])[j] =
            *(const short*)&Qp[(size_t)(h * 32 + quad * 8 + j) * 1024 + q0 + t * 16 + l16];

  float m_run[2] = {-1e30f, -1e30f}, l_run[2] = {0.f, 0.f};
  float4v oacc[2][4];
  #pragma unroll
  for (int t = 0; t < 2; t++)
    #pragma unroll
    for (int dt = 0; dt < 4; dt++) oacc[t][dt] = (float4v){0.f, 0.f, 0.f, 0.f};

  for (int mc = 0; mc < 8; mc++) {
    // S MFMAs: wave's 32 keys x 32 q. A-frags straight from global K^T.
    float sc[2][2][4];                 // [key_sub][q_sub][r]
    #pragma unroll
    for (int s = 0; s < 2; s++) {
      const bf16* krow = KTp + (size_t)(mc * 128 + (wave * 2 + s) * 16 + l16) * 64;
      short8 af0 = *(const short8*)&krow[quad * 8];
      short8 af1 = *(const short8*)&krow[32 + quad * 8];
      #pragma unroll
      for (int t = 0; t < 2; t++) {
        float4v a = (float4v){0.f, 0.f, 0.f, 0.f};
        a = __builtin_amdgcn_mfma_f32_16x16x32_bf16(af0, qf[t][0], a, 0, 0, 0);
        a = __builtin_amdgcn_mfma_f32_16x16x32_bf16(af1, qf[t][1], a, 0, 0, 0);
        #pragma unroll
        for (int r = 0; r < 4; r++) sc[s][t][r] = a[r];
      }
    }

    // V B-frags straight from global (issued early; latency hides under softmax)
    short8 vf[4];
    #pragma unroll
    for (int dt = 0; dt < 4; dt++)
      vf[dt] = *(const short8*)&Vp[(size_t)(dt * 16 + l16) * 1024 + mc * 128 + wave * 32 + quad * 8];

    // online softmax per q-subtile
    float alpha[2], pf[2][2][4];
    #pragma unroll
    for (int t = 0; t < 2; t++) {
      float cmax = sc[0][t][0];
      #pragma unroll
      for (int s = 0; s < 2; s++)
        #pragma unroll
        for (int r = 0; r < 4; r++) cmax = fmaxf(cmax, sc[s][t][r]);
      cmax = fmaxf(cmax, __shfl_xor(cmax, 16, 64));
      cmax = fmaxf(cmax, __shfl_xor(cmax, 32, 64));
      float mnew = fmaxf(m_run[t], cmax);
      alpha[t] = __expf(m_run[t] - mnew);
      float psum = 0.f;
      #pragma unroll
      for (int s = 0; s < 2; s++)
        #pragma unroll
        for (int r = 0; r < 4; r++) {
          pf[t][s][r] = __expf(sc[s][t][r] - mnew);
          psum += pf[t][s][r];
        }
      psum += __shfl_xor(psum, 16, 64);
      psum += __shfl_xor(psum, 32, 64);
      l_run[t] = l_run[t] * alpha[t] + psum;
      m_run[t] = mnew;
    }

    // P -> PV A-frag layout via wave-private LDS bounce.
    // Write P[q=t*16+l16][key32=s*16+quad*4+r] (one b64 per (t,s)),
    // read  A[q=l16-rows][k=quad*8+j] as two b128 (contiguous 1KB/wave: no conflicts).
    #pragma unroll
    for (int t = 0; t < 2; t++)
      #pragma unroll
      for (int s = 0; s < 2; s++) {
        short4v pk;
        #pragma unroll
        for (int r = 0; r < 4; r++) {
          bf16 pb = __float2bfloat16(pf[t][s][r]);
          ((short*)&pk)[r] = *(short*)&pb;
        }
        *(short4v*)&Pw[(t * 16 + l16) * 32 + s * 16 + quad * 4] = pk;
      }
    asm volatile("s_waitcnt lgkmcnt(0)" ::: "memory");
    short8 paf[2];
    #pragma unroll
    for (int t = 0; t < 2; t++)
      paf[t] = *(const short8*)&Pw[(t * 16 + l16) * 32 + quad * 8];
    asm volatile("" ::: "memory");   // fence: next chunk's writes must not hoist above these reads

    float al[2][4];
    #pragma unroll
    for (int t = 0; t < 2; t++)
      #pragma unroll
      for (int r = 0; r < 4; r++) al[t][r] = __shfl(alpha[t], quad * 4 + r, 64);

    // PV MFMAs: V frags reused across both q-subtiles
    #pragma unroll
    for (int dt = 0; dt < 4; dt++) {
      #pragma unroll
      for (int t = 0; t < 2; t++) {
        float4v c;
        #pragma unroll
        for (int r = 0; r < 4; r++) c[r] = oacc[t][dt][r] * al[t][r];
        oacc[t][dt] = __builtin_amdgcn_mfma_f32_16x16x32_bf16(paf[t], vf[dt], c, 0, 0, 0);
      }
    }
  }

  // cross-wave combine
  __syncthreads();
  if (quad == 0) {
    #pragma unroll
    for (int t = 0; t < 2; t++) {
      mS[wave * 32 + t * 16 + l16] = m_run[t];
      lS[wave * 32 + t * 16 + l16] = l_run[t];
    }
  }
  #pragma unroll
  for (int t = 0; t < 2; t++)
    #pragma unroll
    for (int dt = 0; dt < 4; dt++)
      #pragma unroll
      for (int r = 0; r < 4; r++)
        Ow[wave * 2080 + (t * 16 + quad * 4 + r) * 65 + dt * 16 + l16] = oacc[t][dt][r];
  __syncthreads();

  bf16* op = oT + (size_t)zb * o_bstride;
  #pragma unroll
  for (int k = 0; k < 8; k++) {
    int idx = k * 256 + tid;
    int q = idx >> 6, d = idx & 63;
    float mstar = mS[q];
    #pragma unroll
    for (int w = 1; w < 4; w++) mstar = fmaxf(mstar, mS[w * 32 + q]);
    float num = 0.f, den = 0.f;
    #pragma unroll
    for (int w = 0; w < 4; w++) {
      float e = __expf(mS[w * 32 + q] - mstar);
      den += lS[w * 32 + q] * e;
      num += Ow[w * 2080 + q * 65 + d] * e;
    }
    op[(size_t)(q0 + q) * 256 + n * 64 + d] = __float2bfloat16(num / den);
  }
}

// proj GEMM on MFMA: out[b][m][l] = Pb[m][:]·o[:][l] + bproj[m] + x, f32 out.
__global__ __launch_bounds__(256) void gemm_proj_mfma(
    const bf16* __restrict__ Pb, const bf16* __restrict__ oT,
    const float* __restrict__ bproj, const float* __restrict__ x,
    float* __restrict__ out, int b_off, size_t o_bstride) {
  __shared__ bf16 As[128][40];
  __shared__ bf16 Bs[128][40];
  int zb = blockIdx.z, b = zb + b_off;
  int m0 = blockIdx.y * 128, l0 = blockIdx.x * 128;
  const bf16* ob = oT + (size_t)zb * o_bstride;
  int tid = threadIdx.x, lane = tid & 63, wave = tid >> 6;
  int l16 = lane & 15, quad = lane >> 4;
  int mi0 = (wave & 1) * 4, nj0 = (wave >> 1) * 4;
  float4v acc[4][4];
  #pragma unroll
  for (int i = 0; i < 4; i++)
    #pragma unroll
    for (int j = 0; j < 4; j++) acc[i][j] = (float4v){0.f, 0.f, 0.f, 0.f};

  for (int kc = 0; kc < 8; kc++) {
    __syncthreads();
    #pragma unroll
    for (int it = 0; it < 2; it++) {
      int s = it * 256 + tid;
      int mm = s >> 2, kk = (s & 3) * 8;
      *(short8*)&As[mm][kk] = *(const short8*)&Pb[(size_t)(m0 + mm) * 256 + kc * 32 + kk];
      *(short8*)&Bs[mm][kk] = *(const short8*)&ob[(size_t)(l0 + mm) * 256 + kc * 32 + kk];
    }
    __syncthreads();
    short8 af[4], bfr[4];
    #pragma unroll
    for (int i = 0; i < 4; i++) af[i]  = *(const short8*)&As[(mi0 + i) * 16 + l16][quad * 8];
    #pragma unroll
    for (int j = 0; j < 4; j++) bfr[j] = *(const short8*)&Bs[(nj0 + j) * 16 + l16][quad * 8];
    #pragma unroll
    for (int i = 0; i < 4; i++)
      #pragma unroll
      for (int j = 0; j < 4; j++)
        acc[i][j] = __builtin_amdgcn_mfma_f32_16x16x32_bf16(af[i], bfr[j], acc[i][j], 0, 0, 0);
  }

  #pragma unroll
  for (int i = 0; i < 4; i++) {
    #pragma unroll
    for (int r = 0; r < 4; r++) {
      int m = m0 + (mi0 + i) * 16 + quad * 4 + r;
      float bias = bproj[m];
      #pragma unroll
      for (int j = 0; j < 4; j++) {
        int l = l0 + (nj0 + j) * 16 + l16;
        size_t idx = (size_t)(b * 256 + m) * 1024 + l;
        out[idx] = acc[i][j][r] + bias + x[idx];
      }
    }
  }
}

extern "C" void kernel_launch(void* const* d_in, const int* in_sizes, int n_in,
                              void* d_out, int out_size, void* d_ws, size_t ws_size,
                              hipStream_t stream) {
  int ix = 0, iga = 1, ibe = 2, iwq = 3, ibq = 4, iwk = 5, ibk = 6,
      iwv = 7, ibv = 8, iwp = 9, ibp = 10;
  if (in_sizes[0] != 4194304) {
    if (in_sizes[10] == 4194304 && in_sizes[1] == 256) {
      ibe = 0; ibk = 1; ibp = 2; ibq = 3; ibv = 4; iga = 5;
      iwk = 6; iwp = 7; iwq = 8; iwv = 9; ix = 10;
    } else if (in_sizes[10] == 4194304 && in_sizes[1] == 65536) {
      ibp = 0; iwp = 1; ibv = 2; iwv = 3; ibk = 4; iwk = 5;
      ibq = 6; iwq = 7; ibe = 8; iga = 9; ix = 10;
    } else {
      for (int i = 0; i < 11; i++) if (in_sizes[i] == 4194304) ix = i;
    }
  }
  const float* x     = (const float*)d_in[ix];
  const float* gamma = (const float*)d_in[iga];
  const float* beta  = (const float*)d_in[ibe];
  const float* wq    = (const float*)d_in[iwq];
  const float* bq    = (const float*)d_in[ibq];
  const float* wk    = (const float*)d_in[iwk];
  const float* bk    = (const float*)d_in[ibk];
  const float* wv    = (const float*)d_in[iwv];
  const float* bv    = (const float*)d_in[ibv];
  const float* wproj = (const float*)d_in[iwp];
  const float* bproj = (const float*)d_in[ibp];
  float* out = (float*)d_out;

  const size_t QKV_B = (size_t)768 * 1024;
  const size_t O_B   = (size_t)256 * 1024;
  char* wsp = (char*)d_ws;
  float2* stats = (float2*)wsp;                        // 4 KB
  bf16* Wb = (bf16*)(wsp + 8192);                      // 384 KB
  bf16* Pb = (bf16*)(wsp + 8192 + 393216);             // 128 KB
  const size_t HT0 = 8192 + 393216 + 131072;
  size_t full_need = HT0 + (size_t)16 * O_B * 2 + (size_t)16 * QKV_B * 2; // ~34.1 MB

  stats_kernel<<<512, 256, 0, stream>>>(x, stats);
  wpack<<<1024, 256, 0, stream>>>(wq, wk, wv, wproj, Wb, Pb);

  if (ws_size >= full_need) {
    bf16* hT  = (bf16*)(wsp + HT0);                    // 8 MB; reused as oT
    bf16* qkv = (bf16*)(wsp + HT0 + 16 * O_B * 2);     // 24 MB
    bf16* oT  = hT;
    gnt_kernel   <<<dim3(16, 4, 16), 256, 0, stream>>>(x, gamma, beta, stats, hT, 0);
    gemm_qkv_mfma<<<dim3(8, 6, 16), 256, 0, stream>>>(hT, Wb, bq, bk, bv, qkv, QKV_B);
    attn_kernel  <<<dim3(32, 4, 16), 256, 0, stream>>>(qkv, oT, QKV_B, O_B);
    gemm_proj_mfma<<<dim3(8, 2, 16), 256, 0, stream>>>(Pb, oT, bproj, x, out, 0, O_B);
  } else {
    bf16* hT  = (bf16*)(wsp + HT0);
    bf16* qkv = (bf16*)(wsp + HT0 + O_B * 2);
    bf16* oT  = hT;
    for (int b = 0; b < 16; b++) {
      gnt_kernel   <<<dim3(16, 4, 1), 256, 0, stream>>>(x, gamma, beta, stats, hT, b);
      gemm_qkv_mfma<<<dim3(8, 6, 1), 256, 0, stream>>>(hT, Wb, bq, bk, bv, qkv, 0);
      attn_kernel  <<<dim3(32, 4, 1), 256, 0, stream>>>(qkv, oT, 0, 0);
      gemm_proj_mfma<<<dim3(8, 2, 1), 256, 0, stream>>>(Pb, oT, bproj, x, out, b, 0);
    }
  }
}